// Round 9
// baseline (103.483 us; speedup 1.0000x reference)
//
#include <hip/hip_runtime.h>
#include <math.h>

// Problem constants (match reference)
#define KOBJ  512
#define NCLS  6
#define QMIN  0.1f
#define EPSF  1e-9f

// k_hits: NBH blocks x 1024 threads, exactly 1 hit/thread (80*1024=81920 >= N)
#define NBH  80
// k_obj: 8 blocks x 1024 threads; 16 waves x 64 lanes; rows per (wave,lane):
#define ROWS_PER (NBH / 16)       // 5
// k_pair tiling (R8-proven shape)
#define KC   64
#define GX   64
#define NTB  (GX * (KOBJ / KC))   // 512 blocks, 2/CU
#define HP   5                    // GX*256*HP = 81920 >= N

// Workspace overlay (~0.9 MB). Every word read is written earlier in the
// same call -> harness 0xAA poison is harmless, no memset node, no atomics.
struct Ws {
    unsigned long long p_packed[NBH][KOBJ];  // per-hit-block argmax keys
    float p_num[NBH][KOBJ];                  // per-hit-block sum payload*pw
    float p_den[NBH][KOBJ];                  // per-hit-block sum pw
    int   p_cnt[NBH][KOBJ];                  // per-hit-block hit counts
    float pnoise[NBH][4];                    // ccSq, noiseBetaSum, noiseCnt
    float kvec[KOBJ * 4];                    // {x0,x1,qw_rep,qw_att} by k_obj
    float pobj[8][4];                        // per-obj-block: flagSum, sum(1-beta_a), sum(payk)
    float pattrep[NTB][2];                   // per-pair-block att, rep (plain stores)
};

__device__ __forceinline__ float clipb(float b) {
    return fminf(fmaxf(b, 1e-6f), 1.0f - 1e-6f);
}

// native-rate transcendentals (~1 ulp; tolerance is 2% absolute ~0.45)
__device__ __forceinline__ float fsqrt(float x)  { return __builtin_amdgcn_sqrtf(x); }
__device__ __forceinline__ float frcp(float x)   { return __builtin_amdgcn_rcpf(x); }
__device__ __forceinline__ float qval(float b) {  // arctanh(b)^2 + qmin
    float at = 0.5f * __logf((1.f + b) * frcp(1.f - b));
    return at * at + QMIN;
}

__device__ __forceinline__ float waveSum(float v) {
#pragma unroll
    for (int o = 32; o > 0; o >>= 1) v += __shfl_down(v, o, 64);
    return v;
}

// ---------------- Kernel 1: per-hit -> per-block LDS -> partial stores ----------
__global__ __launch_bounds__(1024)
void k_hits(const float* __restrict__ beta_in, const float* __restrict__ cc,
            const float* __restrict__ pe,  const float* __restrict__ ppos,
            const float* __restrict__ pt,  const float* __restrict__ pid,
            const int*   __restrict__ tidx,const float* __restrict__ te,
            const float* __restrict__ tpos,const float* __restrict__ tt,
            Ws* __restrict__ ws, int n)
{
    const int b = blockIdx.x, t = threadIdx.x;

    __shared__ unsigned long long lpk[KOBJ];
    __shared__ float lnum[KOBJ], lden[KOBJ];
    __shared__ int   lcnt[KOBJ];
    for (int k = t; k < KOBJ; k += 1024) { lpk[k] = 0ull; lnum[k] = 0.f; lden[k] = 0.f; lcnt[k] = 0; }
    __syncthreads();

    float ccs = 0.f, nb = 0.f, nc = 0.f;
    const int i = b * 1024 + t;             // exactly one hit per thread
    if (i < n) {
        float bb = clipb(beta_in[i]);
        float c0 = cc[2*i], c1 = cc[2*i+1];
        ccs = c0*c0 + c1*c1;
        int k = tidx[i];
        if (k >= 0) {
            // argmax-beta, first-index tie-break (larger ~i == smaller i)
            unsigned long long key =
                ((unsigned long long)__float_as_uint(bb) << 32) | (unsigned)(~i);
            atomicMax(&lpk[k], key);
            atomicAdd(&lcnt[k], 1);

            float tei   = te[i];
            float ediff = fabsf(tei - pe[i]);
            float el = 10.f * __expf(-0.1f * ediff * ediff) + 0.01f * ediff;
            { float x = el * 0.1f; if (x > 1.f) x = __logf(x + 1.f); el = x * 10.f; }

            float dx  = tpos[2*i]   - ppos[2*i];
            float dy  = tpos[2*i+1] - ppos[2*i+1];
            float d2p = dx*dx + dy*dy;
            float hx  = fsqrt(d2p * 0.01f + 0.01f);
            float pl  = (hx < 10.f) ? hx*hx : 100.f + 20.f*(hx - 10.f);
            { float x = pl * (1.f/3.f); if (x > 1.f) x = __logf(x + 1.f); pl = x * 3.f; }

            float td  = tt[i] - pt[i];
            float atd = fabsf(td);
            float tl  = (atd < 2.f) ? td*td : 4.f + 4.f*(atd - 2.f);
            { float x = tl * (1.f/6.f); if (x > 1.f) x = __logf(x + 1.f); tl = x * 6.f; }

            float cls = 0.f;
#pragma unroll
            for (int j = 0; j < NCLS; ++j) { float v = pid[i*NCLS + j]; cls += v*v; }
            cls *= (1e-8f / (float)NCLS);

            float payload = el + pl + tl + cls;
            float ew = (tei > 10.f) ? 1.f : (tei - 0.5f) * (1.f / 9.5f);
            ew = fmaxf(ew, 0.f);
            float pw = bb * ew;
            atomicAdd(&lnum[k], payload * pw);
            atomicAdd(&lden[k], pw);
        } else {
            nb = bb; nc = 1.f;
        }
    }
    __syncthreads();

    // coalesced partial flush (lanes sweep k, fixed row b) — plain stores
    if (t < KOBJ) {
        ws->p_packed[b][t] = lpk[t];
        ws->p_num[b][t]    = lnum[t];
        ws->p_den[b][t]    = lden[t];
        ws->p_cnt[b][t]    = lcnt[t];
    }

    __shared__ float sred[3][16];
    float A = waveSum(ccs), B = waveSum(nb), C = waveSum(nc);
    int lane = t & 63, wv = t >> 6;
    if (lane == 0) { sred[0][wv] = A; sred[1][wv] = B; sred[2][wv] = C; }
    __syncthreads();
    if (t == 0) {
        float a = 0.f, x = 0.f, y = 0.f;
        for (int j = 0; j < 16; ++j) { a += sred[0][j]; x += sred[1][j]; y += sred[2][j]; }
        ws->pnoise[b][0] = a; ws->pnoise[b][1] = x; ws->pnoise[b][2] = y;
    }
}

// ---------------- Kernel 2: reduce partials ONCE -> kvec + pobj ----------------
// 8 blocks x 1024 threads; block owns 64 objects; 16 waves x 64 lanes,
// each (wv,lane) covers ROWS_PER partial rows of object kbase+lane.
__global__ __launch_bounds__(1024)
void k_obj(const float* __restrict__ beta_in, const float* __restrict__ cc,
           Ws* __restrict__ ws, int n)
{
    const int t = threadIdx.x, lane = t & 63, wv = t >> 6;
    const int k = blockIdx.x * 64 + lane;

    unsigned long long pk = 0ull;
    float nm = 0.f, dn = 0.f;
    int   ct = 0;
#pragma unroll
    for (int j = wv * ROWS_PER; j < (wv + 1) * ROWS_PER; ++j) {
        unsigned long long v = ws->p_packed[j][k];     // 64 consecutive k: coalesced
        pk = (v > pk) ? v : pk;
        nm += ws->p_num[j][k];
        dn += ws->p_den[j][k];
        ct += ws->p_cnt[j][k];
    }
    __shared__ unsigned long long spk[16][64];
    __shared__ float snum[16][64], sden[16][64];
    __shared__ int   scnt[16][64];
    spk[wv][lane] = pk; snum[wv][lane] = nm; sden[wv][lane] = dn; scnt[wv][lane] = ct;
    __syncthreads();

    if (wv == 0) {
#pragma unroll
        for (int j = 1; j < 16; ++j) {
            unsigned long long v = spk[j][lane];
            pk = (v > pk) ? v : pk;
            nm += snum[j][lane]; dn += sden[j][lane]; ct += scnt[j][lane];
        }
        float flag = 0.f, bsum = 0.f, payk = 0.f;
        float q_a = 0.f, x0 = 0.f, x1 = 0.f;
        if (ct > 0) {
            flag = 1.f;
            unsigned idx = ~(unsigned)(pk & 0xffffffffull);
            float bb = clipb(beta_in[idx]);
            bsum = 1.f - bb;
            q_a = qval(bb);
            x0 = cc[2*idx]; x1 = cc[2*idx + 1];
            payk = nm / (dn + EPSF);
        }
        // 1/n_obj deferred to k_final
        ((float4*)ws->kvec)[k] = make_float4(
            x0, x1,
            flag * q_a / ((float)n - (float)ct + EPSF),
            flag * q_a / ((float)ct + EPSF));
        float f  = waveSum(flag);
        float bs = waveSum(bsum);
        float ps = waveSum(payk);
        if (lane == 0) {
            ws->pobj[blockIdx.x][0] = f;
            ws->pobj[blockIdx.x][1] = bs;
            ws->pobj[blockIdx.x][2] = ps;
        }
    }
}

// ---------------- Kernel 3: N x K pairwise -> per-block plain stores ----------
__global__ __launch_bounds__(256)
void k_pair(const float* __restrict__ beta_in, const float* __restrict__ cc,
            const int* __restrict__ tidx, Ws* __restrict__ ws, int n)
{
    const int b = blockIdx.x, t = threadIdx.x;
    const int lane = t & 63, wv = t >> 6;
    const int kchunk = b / GX;
    const int xi     = b - kchunk * GX;
    const int kbase  = kchunk * KC;

    __shared__ float4 sk[KC];
    if (t < KC) sk[t] = ((const float4*)ws->kvec)[kbase + t];

    const int xspan = GX * 256;          // 16384
    const int i0 = xi * 256 + t;
    float c0[HP], c1[HP], qq[HP], acc[HP];
    int   k0[HP];
#pragma unroll
    for (int j = 0; j < HP; ++j) {
        int i = i0 + j * xspan;
        bool v = (i < n);
        // invalid lanes parked far away -> relu(1-r)==0; k0=-1 guards att
        c0[j] = v ? cc[2*i]     : 1e30f;
        c1[j] = v ? cc[2*i + 1] : 1e30f;
        float bb = v ? clipb(beta_in[i]) : 0.5f;
        qq[j] = qval(bb);
        k0[j] = v ? tidx[i] : -1;
        acc[j] = 0.f;
    }
    __syncthreads();

#pragma unroll 4
    for (int k = 0; k < KC; ++k) {
        float4 kv = sk[k];
#pragma unroll
        for (int j = 0; j < HP; ++j) {
            float dx = c0[j] - kv.x, dy = c1[j] - kv.y;
            float d2e = fmaf(dx, dx, fmaf(dy, dy, 1e-6f));
            float r   = fsqrt(d2e);
            acc[j] = fmaf(fmaxf(1.f - r, 0.f), kv.z, acc[j]);
        }
    }

    float att = 0.f, rep = 0.f;
#pragma unroll
    for (int j = 0; j < HP; ++j) {
        int kk = k0[j] - kbase;
        if (kk >= 0 && kk < KC) {
            // remove self-repulsion with the same fp formula (error ~ulp, << tol)
            float4 kv = sk[kk];
            float dx = c0[j] - kv.x, dy = c1[j] - kv.y;
            float d2e = fmaf(dx, dx, fmaf(dy, dy, 1e-6f));
            float r   = fsqrt(d2e);
            acc[j] -= fmaxf(1.f - r, 0.f) * kv.z;
            // attraction uses d2 WITHOUT the 1e-6 (matches reference)
            float d2 = fmaf(dx, dx, dy * dy);
            att = fmaf(d2 * kv.w, qq[j], att);
        }
        rep = fmaf(acc[j], qq[j], rep);
    }

    __shared__ float sred[2][4];
    float A = waveSum(att), R = waveSum(rep);
    if (lane == 0) { sred[0][wv] = A; sred[1][wv] = R; }
    __syncthreads();
    if (t == 0) {
        float sa = 0.f, sr = 0.f;
        for (int j = 0; j < 4; ++j) { sa += sred[0][j]; sr += sred[1][j]; }
        ws->pattrep[b][0] = sa;            // plain stores — no atomics, no fence
        ws->pattrep[b][1] = sr;
    }
}

// ---------------- Kernel 4: final combine (1 block x 512) ----------------
__global__ __launch_bounds__(512)
void k_final(Ws* __restrict__ ws, float* __restrict__ out, int n)
{
    const int t = threadIdx.x, lane = t & 63, wv = t >> 6;

    float att = ws->pattrep[t][0];         // NTB == 512 == blockDim
    float rep = ws->pattrep[t][1];
    float ccs = 0.f, nB = 0.f, nC = 0.f;
    if (t < NBH) { ccs = ws->pnoise[t][0]; nB = ws->pnoise[t][1]; nC = ws->pnoise[t][2]; }
    float fS = 0.f, bS = 0.f, pS = 0.f;
    if (t < 8)   { fS = ws->pobj[t][0]; bS = ws->pobj[t][1]; pS = ws->pobj[t][2]; }

    att = waveSum(att); rep = waveSum(rep);
    ccs = waveSum(ccs); nB = waveSum(nB); nC = waveSum(nC);
    fS = waveSum(fS); bS = waveSum(bS); pS = waveSum(pS);

    __shared__ float fin[8][8];
    if (lane == 0) {
        fin[0][wv] = att; fin[1][wv] = rep; fin[2][wv] = ccs; fin[3][wv] = nB;
        fin[4][wv] = nC;  fin[5][wv] = fS;  fin[6][wv] = bS;  fin[7][wv] = pS;
    }
    __syncthreads();
    if (t == 0) {
        float v[8];
        for (int m = 0; m < 8; ++m) {
            v[m] = 0.f;
            for (int j = 0; j < 8; ++j) v[m] += fin[m][j];
        }
        float n_obj = v[5] + EPSF;
        out[0] = (v[0] + v[1] + v[6] + v[7]) / n_obj   // att + rep + L_beta + L_pay
               + v[3] / (v[4] + EPSF)                  // L_noise
               + 0.001f * v[2] / (float)(2 * n);       // L_cc
    }
}

extern "C" void kernel_launch(void* const* d_in, const int* in_sizes, int n_in,
                              void* d_out, int out_size, void* d_ws, size_t ws_size,
                              hipStream_t stream)
{
    const float* pred_beta    = (const float*)d_in[0];
    const float* pred_ccoords = (const float*)d_in[1];
    const float* pred_energy  = (const float*)d_in[2];
    const float* pred_pos     = (const float*)d_in[3];
    const float* pred_time    = (const float*)d_in[4];
    const float* pred_id      = (const float*)d_in[5];
    const int*   t_idx        = (const int*)d_in[6];
    const float* t_energy     = (const float*)d_in[7];
    const float* t_pos        = (const float*)d_in[8];
    const float* t_time       = (const float*)d_in[9];
    // t_pid (d_in[10]) unused by the reference's classification loss

    float* out = (float*)d_out;
    Ws* ws = (Ws*)d_ws;
    int n = in_sizes[0];   // 80000 (tiling covers n <= 81920)

    k_hits<<<NBH, 1024, 0, stream>>>(pred_beta, pred_ccoords, pred_energy, pred_pos,
                                     pred_time, pred_id, t_idx, t_energy, t_pos,
                                     t_time, ws, n);
    k_obj<<<8, 1024, 0, stream>>>(pred_beta, pred_ccoords, ws, n);
    k_pair<<<NTB, 256, 0, stream>>>(pred_beta, pred_ccoords, t_idx, ws, n);
    k_final<<<1, 512, 0, stream>>>(ws, out, n);
}

// Round 10
// 99.453 us; speedup vs baseline: 1.0405x; 1.0405x over previous
//
#include <hip/hip_runtime.h>
#include <math.h>

// Problem constants (match reference)
#define KOBJ  512
#define NCLS  6
#define QMIN  0.1f
#define EPSF  1e-9f

// k_hits: NBH blocks x 1024 threads, exactly 1 hit/thread (80*1024=81920 >= N)
#define NBH  80
// k_pair tiling (R8-proven shape) + fused stage-A (R5-proven pattern)
#define KC   64
#define GX   64
#define NTB  (GX * (KOBJ / KC))   // 512 blocks, 2/CU
#define HP   5                    // GX*256*HP = 81920 >= N
#define AROWS (NBH / 4)           // 20 partial rows per (wave,lane) in stage A

// Workspace overlay (~0.9 MB). Every word read is written earlier in the
// same call -> harness 0xAA poison is harmless, no memset node, no atomics.
struct Ws {
    unsigned long long p_packed[NBH][KOBJ];  // per-hit-block argmax keys
    float p_num[NBH][KOBJ];                  // per-hit-block sum payload*pw
    float p_den[NBH][KOBJ];                  // per-hit-block sum pw
    int   p_cnt[NBH][KOBJ];                  // per-hit-block hit counts
    float pnoise[NBH][4];                    // ccSq, noiseBetaSum, noiseCnt
    float pobj[KOBJ / KC][4];                // per-chunk: flagSum, sum(1-beta_a), sum(payk)
    float pattrep[NTB][2];                   // per-pair-block att, rep (plain stores)
};

__device__ __forceinline__ float clipb(float b) {
    return fminf(fmaxf(b, 1e-6f), 1.0f - 1e-6f);
}

// native-rate transcendentals (~1 ulp; tolerance is 2% absolute ~0.45)
__device__ __forceinline__ float fsqrt(float x)  { return __builtin_amdgcn_sqrtf(x); }
__device__ __forceinline__ float frcp(float x)   { return __builtin_amdgcn_rcpf(x); }
__device__ __forceinline__ float qval(float b) {  // arctanh(b)^2 + qmin
    float at = 0.5f * __logf((1.f + b) * frcp(1.f - b));
    return at * at + QMIN;
}

__device__ __forceinline__ float waveSum(float v) {
#pragma unroll
    for (int o = 32; o > 0; o >>= 1) v += __shfl_down(v, o, 64);
    return v;
}

// ---------------- Kernel 1: per-hit -> per-block LDS -> partial stores ----------
__global__ __launch_bounds__(1024)
void k_hits(const float* __restrict__ beta_in, const float* __restrict__ cc,
            const float* __restrict__ pe,  const float* __restrict__ ppos,
            const float* __restrict__ pt,  const float* __restrict__ pid,
            const int*   __restrict__ tidx,const float* __restrict__ te,
            const float* __restrict__ tpos,const float* __restrict__ tt,
            Ws* __restrict__ ws, int n)
{
    const int b = blockIdx.x, t = threadIdx.x;

    __shared__ unsigned long long lpk[KOBJ];
    __shared__ float lnum[KOBJ], lden[KOBJ];
    __shared__ int   lcnt[KOBJ];
    for (int k = t; k < KOBJ; k += 1024) { lpk[k] = 0ull; lnum[k] = 0.f; lden[k] = 0.f; lcnt[k] = 0; }
    __syncthreads();

    float ccs = 0.f, nb = 0.f, nc = 0.f;
    const int i = b * 1024 + t;             // exactly one hit per thread
    if (i < n) {
        float bb = clipb(beta_in[i]);
        float c0 = cc[2*i], c1 = cc[2*i+1];
        ccs = c0*c0 + c1*c1;
        int k = tidx[i];
        if (k >= 0) {
            // argmax-beta, first-index tie-break (larger ~i == smaller i)
            unsigned long long key =
                ((unsigned long long)__float_as_uint(bb) << 32) | (unsigned)(~i);
            atomicMax(&lpk[k], key);
            atomicAdd(&lcnt[k], 1);

            float tei   = te[i];
            float ediff = fabsf(tei - pe[i]);
            float el = 10.f * __expf(-0.1f * ediff * ediff) + 0.01f * ediff;
            { float x = el * 0.1f; if (x > 1.f) x = __logf(x + 1.f); el = x * 10.f; }

            float dx  = tpos[2*i]   - ppos[2*i];
            float dy  = tpos[2*i+1] - ppos[2*i+1];
            float d2p = dx*dx + dy*dy;
            float hx  = fsqrt(d2p * 0.01f + 0.01f);
            float pl  = (hx < 10.f) ? hx*hx : 100.f + 20.f*(hx - 10.f);
            { float x = pl * (1.f/3.f); if (x > 1.f) x = __logf(x + 1.f); pl = x * 3.f; }

            float td  = tt[i] - pt[i];
            float atd = fabsf(td);
            float tl  = (atd < 2.f) ? td*td : 4.f + 4.f*(atd - 2.f);
            { float x = tl * (1.f/6.f); if (x > 1.f) x = __logf(x + 1.f); tl = x * 6.f; }

            float cls = 0.f;
#pragma unroll
            for (int j = 0; j < NCLS; ++j) { float v = pid[i*NCLS + j]; cls += v*v; }
            cls *= (1e-8f / (float)NCLS);

            float payload = el + pl + tl + cls;
            float ew = (tei > 10.f) ? 1.f : (tei - 0.5f) * (1.f / 9.5f);
            ew = fmaxf(ew, 0.f);
            float pw = bb * ew;
            atomicAdd(&lnum[k], payload * pw);
            atomicAdd(&lden[k], pw);
        } else {
            nb = bb; nc = 1.f;
        }
    }
    __syncthreads();

    // coalesced partial flush (lanes sweep k, fixed row b) — plain stores
    if (t < KOBJ) {
        ws->p_packed[b][t] = lpk[t];
        ws->p_num[b][t]    = lnum[t];
        ws->p_den[b][t]    = lden[t];
        ws->p_cnt[b][t]    = lcnt[t];
    }

    __shared__ float sred[3][16];
    float A = waveSum(ccs), B = waveSum(nb), C = waveSum(nc);
    int lane = t & 63, wv = t >> 6;
    if (lane == 0) { sred[0][wv] = A; sred[1][wv] = B; sred[2][wv] = C; }
    __syncthreads();
    if (t == 0) {
        float a = 0.f, x = 0.f, y = 0.f;
        for (int j = 0; j < 16; ++j) { a += sred[0][j]; x += sred[1][j]; y += sred[2][j]; }
        ws->pnoise[b][0] = a; ws->pnoise[b][1] = x; ws->pnoise[b][2] = y;
    }
}

// ---------------- Kernel 2: fused per-chunk setup + N x K pairwise ----------
__global__ __launch_bounds__(256)
void k_pair(const float* __restrict__ beta_in, const float* __restrict__ cc,
            const int* __restrict__ tidx, Ws* __restrict__ ws, int n)
{
    const int b = blockIdx.x, t = threadIdx.x;
    const int lane = t & 63, wv = t >> 6;
    const int kchunk = b / GX;
    const int xi     = b - kchunk * GX;
    const int kbase  = kchunk * KC;

    // ---- Hoisted per-hit global loads: overlap stage-A latency (G7) ----
    const int xspan = GX * 256;          // 16384
    const int i0 = xi * 256 + t;
    float c0[HP], c1[HP], bH[HP];
    int   k0[HP];
#pragma unroll
    for (int j = 0; j < HP; ++j) {
        int i = i0 + j * xspan;
        bool v = (i < n);
        // invalid lanes parked far away -> relu(1-r)==0; k0=-1 guards att
        c0[j] = v ? cc[2*i]     : 1e30f;
        c1[j] = v ? cc[2*i + 1] : 1e30f;
        bH[j] = v ? beta_in[i]  : 0.5f;
        k0[j] = v ? tidx[i] : -1;
    }

    // ---- Stage A: reduce NBH partials for this chunk's KC objects -> LDS kvec ----
    __shared__ float4 sk[KC];                        // {x0,x1,qw_rep,qw_att}
    __shared__ unsigned long long spk[4][KC];
    __shared__ float snum[4][KC], sden[4][KC];
    __shared__ int   scnt[4][KC];
    {
        int k = kbase + lane;
        unsigned long long pk = 0ull;
        float nm = 0.f, dn = 0.f; int ct = 0;
#pragma unroll 4
        for (int j = wv * AROWS; j < (wv + 1) * AROWS; ++j) {
            unsigned long long v = ws->p_packed[j][k];   // 64 consecutive k: coalesced
            pk = (v > pk) ? v : pk;
            nm += ws->p_num[j][k];
            dn += ws->p_den[j][k];
            ct += ws->p_cnt[j][k];
        }
        spk[wv][lane] = pk; snum[wv][lane] = nm; sden[wv][lane] = dn; scnt[wv][lane] = ct;
    }
    __syncthreads();
    if (wv == 0) {
        unsigned long long pk = spk[0][lane];
        float nm = snum[0][lane], dn = sden[0][lane];
        int ct = scnt[0][lane];
#pragma unroll
        for (int j = 1; j < 4; ++j) {
            unsigned long long v = spk[j][lane];
            pk = (v > pk) ? v : pk;
            nm += snum[j][lane]; dn += sden[j][lane]; ct += scnt[j][lane];
        }
        float flag = 0.f, bsum = 0.f, payk = 0.f;
        float q_a = 0.f, x0 = 0.f, x1 = 0.f;
        if (ct > 0) {
            flag = 1.f;
            unsigned idx = ~(unsigned)(pk & 0xffffffffull);
            float bb = clipb(beta_in[idx]);
            bsum = 1.f - bb;
            q_a = qval(bb);
            x0 = cc[2*idx]; x1 = cc[2*idx + 1];
            payk = nm / (dn + EPSF);
        }
        // 1/n_obj deferred to k_final
        sk[lane] = make_float4(x0, x1,
                               flag * q_a / ((float)n - (float)ct + EPSF),
                               flag * q_a / ((float)ct + EPSF));
        if (xi == 0) {   // chunk leader publishes cross-K partials (plain stores)
            float f  = waveSum(flag);
            float bs = waveSum(bsum);
            float ps = waveSum(payk);
            if (lane == 0) {
                ws->pobj[kchunk][0] = f;
                ws->pobj[kchunk][1] = bs;
                ws->pobj[kchunk][2] = ps;
            }
        }
    }
    __syncthreads();

    // ---- Stage B: HP hits x KC objects ----
    float qq[HP], acc[HP];
#pragma unroll
    for (int j = 0; j < HP; ++j) {
        qq[j] = qval(clipb(bH[j]));
        acc[j] = 0.f;
    }

#pragma unroll 4
    for (int k = 0; k < KC; ++k) {
        float4 kv = sk[k];
#pragma unroll
        for (int j = 0; j < HP; ++j) {
            float dx = c0[j] - kv.x, dy = c1[j] - kv.y;
            float d2e = fmaf(dx, dx, fmaf(dy, dy, 1e-6f));
            float r   = fsqrt(d2e);
            acc[j] = fmaf(fmaxf(1.f - r, 0.f), kv.z, acc[j]);
        }
    }

    float att = 0.f, rep = 0.f;
#pragma unroll
    for (int j = 0; j < HP; ++j) {
        int kk = k0[j] - kbase;
        if (kk >= 0 && kk < KC) {
            // remove self-repulsion with the same fp formula (error ~ulp, << tol)
            float4 kv = sk[kk];
            float dx = c0[j] - kv.x, dy = c1[j] - kv.y;
            float d2e = fmaf(dx, dx, fmaf(dy, dy, 1e-6f));
            float r   = fsqrt(d2e);
            acc[j] -= fmaxf(1.f - r, 0.f) * kv.z;
            // attraction uses d2 WITHOUT the 1e-6 (matches reference)
            float d2 = fmaf(dx, dx, dy * dy);
            att = fmaf(d2 * kv.w, qq[j], att);
        }
        rep = fmaf(acc[j], qq[j], rep);
    }

    __shared__ float sred[2][4];
    float A = waveSum(att), R = waveSum(rep);
    if (lane == 0) { sred[0][wv] = A; sred[1][wv] = R; }
    __syncthreads();
    if (t == 0) {
        float sa = 0.f, sr = 0.f;
        for (int j = 0; j < 4; ++j) { sa += sred[0][j]; sr += sred[1][j]; }
        ws->pattrep[b][0] = sa;            // plain stores — no atomics, no fence
        ws->pattrep[b][1] = sr;
    }
}

// ---------------- Kernel 3: final combine (1 block x 512) ----------------
__global__ __launch_bounds__(512)
void k_final(Ws* __restrict__ ws, float* __restrict__ out, int n)
{
    const int t = threadIdx.x, lane = t & 63, wv = t >> 6;

    float att = ws->pattrep[t][0];         // NTB == 512 == blockDim
    float rep = ws->pattrep[t][1];
    float ccs = 0.f, nB = 0.f, nC = 0.f;
    if (t < NBH) { ccs = ws->pnoise[t][0]; nB = ws->pnoise[t][1]; nC = ws->pnoise[t][2]; }
    float fS = 0.f, bS = 0.f, pS = 0.f;
    if (t < KOBJ / KC) { fS = ws->pobj[t][0]; bS = ws->pobj[t][1]; pS = ws->pobj[t][2]; }

    att = waveSum(att); rep = waveSum(rep);
    ccs = waveSum(ccs); nB = waveSum(nB); nC = waveSum(nC);
    fS = waveSum(fS); bS = waveSum(bS); pS = waveSum(pS);

    __shared__ float fin[8][8];
    if (lane == 0) {
        fin[0][wv] = att; fin[1][wv] = rep; fin[2][wv] = ccs; fin[3][wv] = nB;
        fin[4][wv] = nC;  fin[5][wv] = fS;  fin[6][wv] = bS;  fin[7][wv] = pS;
    }
    __syncthreads();
    if (t == 0) {
        float v[8];
        for (int m = 0; m < 8; ++m) {
            v[m] = 0.f;
            for (int j = 0; j < 8; ++j) v[m] += fin[m][j];
        }
        float n_obj = v[5] + EPSF;
        out[0] = (v[0] + v[1] + v[6] + v[7]) / n_obj   // att + rep + L_beta + L_pay
               + v[3] / (v[4] + EPSF)                  // L_noise
               + 0.001f * v[2] / (float)(2 * n);       // L_cc
    }
}

extern "C" void kernel_launch(void* const* d_in, const int* in_sizes, int n_in,
                              void* d_out, int out_size, void* d_ws, size_t ws_size,
                              hipStream_t stream)
{
    const float* pred_beta    = (const float*)d_in[0];
    const float* pred_ccoords = (const float*)d_in[1];
    const float* pred_energy  = (const float*)d_in[2];
    const float* pred_pos     = (const float*)d_in[3];
    const float* pred_time    = (const float*)d_in[4];
    const float* pred_id      = (const float*)d_in[5];
    const int*   t_idx        = (const int*)d_in[6];
    const float* t_energy     = (const float*)d_in[7];
    const float* t_pos        = (const float*)d_in[8];
    const float* t_time       = (const float*)d_in[9];
    // t_pid (d_in[10]) unused by the reference's classification loss

    float* out = (float*)d_out;
    Ws* ws = (Ws*)d_ws;
    int n = in_sizes[0];   // 80000 (tiling covers n <= 81920)

    k_hits<<<NBH, 1024, 0, stream>>>(pred_beta, pred_ccoords, pred_energy, pred_pos,
                                     pred_time, pred_id, t_idx, t_energy, t_pos,
                                     t_time, ws, n);
    k_pair<<<NTB, 256, 0, stream>>>(pred_beta, pred_ccoords, t_idx, ws, n);
    k_final<<<1, 512, 0, stream>>>(ws, out, n);
}